// Round 4
// baseline (4217.130 us; speedup 1.0000x reference)
//
#include <hip/hip_runtime.h>

typedef unsigned short u16;
typedef unsigned int u32;
typedef __attribute__((ext_vector_type(8))) short bf16x8;
typedef __attribute__((ext_vector_type(4))) float f32x4;

#define DEVI __device__ __forceinline__

DEVI u16 f2bf(float f){
  union { float f; u32 u; } v; v.f = f;
  u32 r = v.u + 0x7fffu + ((v.u >> 16) & 1u);
  return (u16)(r >> 16);
}
DEVI float bf2f(u16 u){
  union { u32 u; float f; } v; v.u = ((u32)u) << 16; return v.f;
}
DEVI u32 pk2(float a, float b){ return (u32)f2bf(a) | ((u32)f2bf(b) << 16); }

// ---------------- f32 -> bf16 weight conversion (RNE, same as pk2 path) ----------------
__global__ __launch_bounds__(256) void k_conv(const float* __restrict__ in,
    u16* __restrict__ out, int n4){
  int i = blockIdx.x*256 + threadIdx.x;
  if (i < n4){
    float4 v = ((const float4*)in)[i];
    ushort4 o;
    o.x = f2bf(v.x); o.y = f2bf(v.y); o.z = f2bf(v.z); o.w = f2bf(v.w);
    ((ushort4*)out)[i] = o;
  }
}

// ---------------- embedding gather ----------------
__global__ __launch_bounds__(256) void k_embed(const int* __restrict__ idx,
    const float* __restrict__ emb, float* __restrict__ x, float* __restrict__ x0){
  int row = blockIdx.x; int tid = threadIdx.x;
  long tok = idx[row];
  float4 v = *(const float4*)(emb + (size_t)tok*1024 + tid*4);
  *(float4*)(x  + (size_t)row*1024 + tid*4) = v;
  *(float4*)(x0 + (size_t)row*1024 + tid*4) = v;
}

// ---------------- rope tables ----------------
__global__ __launch_bounds__(256) void k_ropetab(float* __restrict__ ct, float* __restrict__ st){
  int i = blockIdx.x*256 + threadIdx.x;   // 1024*64
  int d = i & 63, t = i >> 6;
  float fr = __powf(10000.f, -(float)(d & 31) * (1.f/32.f));
  float ang = (float)t * fr;
  ct[i] = cosf(ang);
  st[i] = sinf(ang);
}

// ---------------- rmsnorm (f32 in, bf16 out) ----------------
__global__ __launch_bounds__(256) void k_rms(const float* __restrict__ x,
    const float* __restrict__ w, u16* __restrict__ out){
  int row = blockIdx.x, tid = threadIdx.x;
  const float* xr = x + (size_t)row*1024;
  float4 v = *(const float4*)(xr + tid*4);
  float ss = v.x*v.x + v.y*v.y + v.z*v.z + v.w*v.w;
  #pragma unroll
  for (int m=1; m<64; m<<=1) ss += __shfl_xor(ss, m, 64);
  __shared__ float red[4];
  if ((tid & 63) == 0) red[tid>>6] = ss;
  __syncthreads();
  float tot = red[0]+red[1]+red[2]+red[3];
  float nrm = rsqrtf(tot*(1.f/1024.f) + 1e-6f);
  float4 wv = *(const float4*)(w + tid*4);
  ushort4 o;
  o.x = f2bf(v.x*nrm*wv.x); o.y = f2bf(v.y*nrm*wv.y);
  o.z = f2bf(v.z*nrm*wv.z); o.w = f2bf(v.w*nrm*wv.w);
  *(ushort4*)(out + (size_t)row*1024 + tid*4) = o;
}

// ---------------- ve gate (odd layers) ----------------
__global__ __launch_bounds__(256) void k_gate(const u16* __restrict__ h,
    const float* __restrict__ vw, float* __restrict__ gate){
  int i = blockIdx.x*256 + threadIdx.x;   // 2048*16
  int hh = i & 15, row = i >> 4;
  const u16* hp = h + (size_t)row*1024;
  const float* wp = vw + hh*32;
  float s = 0.f;
  #pragma unroll
  for (int c=0; c<32; c++) s += bf2f(hp[c]) * wp[c];
  gate[i] = 2.f / (1.f + expf(-s));
}

// ---------------- rope + ve add, write head-major bf16 q/k/v ----------------
__global__ __launch_bounds__(256) void k_ropeve(const float* __restrict__ qkv,
    const float* __restrict__ ct, const float* __restrict__ st,
    const float* __restrict__ gate, const float* __restrict__ x0,
    u16* __restrict__ Qb, u16* __restrict__ Kb, u16* __restrict__ Vb, int use_gate){
  int i = blockIdx.x*256 + threadIdx.x;   // 2048*16*32
  int j = i & 31; int h = (i>>5) & 15; int row = i >> 9;
  int b = row >> 10, t = row & 1023;
  const float* qp = qkv + (size_t)row*3072 + h*64 + 2*j;
  float q0v = qp[0],    q1v = qp[1];
  float k0v = qp[1024], k1v = qp[1025];
  float v0v = qp[2048], v1v = qp[2049];
  int ti = t*64 + 2*j;
  float c0 = ct[ti], c1 = ct[ti+1], s0 = st[ti], s1 = st[ti+1];
  float qr0 = q0v*c0 - q1v*s0, qr1 = q1v*c1 + q0v*s1;
  float kr0 = k0v*c0 - k1v*s0, kr1 = k1v*c1 + k0v*s1;
  if (use_gate){
    float g = gate[row*16 + h];
    const float* xp = x0 + (size_t)row*1024 + h*64 + 2*j;
    v0v += g*xp[0]; v1v += g*xp[1];
  }
  size_t ob = ((size_t)(b*16 + h)*1024 + t)*64 + 2*j;
  ushort2 qo; qo.x = f2bf(qr0); qo.y = f2bf(qr1); *(ushort2*)(Qb + ob) = qo;
  ushort2 ko; ko.x = f2bf(kr0); ko.y = f2bf(kr1); *(ushort2*)(Kb + ob) = ko;
  ushort2 vo; vo.x = f2bf(v0v); vo.y = f2bf(v1v); *(ushort2*)(Vb + ob) = vo;
}

// ---------------- GEMM: C[M,N] = A[M,K](bf16) * W[N,K]^T ----------------
// WBF=1: W is bf16 (pre-converted); WBF=0: W is f32, packed inline.
// EPI 0: C f32 = acc ; 1: C f32 += acc ; 2: C bf16 = silu(acc)*R ; 3: C f32 = 30*tanh(acc/30)
template<int EPI, int WBF>
__global__ __launch_bounds__(256) void k_gemm(const u16* __restrict__ A,
    const void* __restrict__ Wv, void* __restrict__ Cout, const float* __restrict__ R,
    int N, int K){
  __shared__ __align__(16) u16 As[128][40];
  __shared__ __align__(16) u16 Ws[128][40];
  const int row0 = blockIdx.x*128, col0 = blockIdx.y*128;
  const int tid = threadIdx.x;
  const int w = tid>>6, lane = tid&63, g = lane>>4, r16 = lane&15;
  const int wr = (w>>1)*64, wc = (w&1)*64;
  f32x4 acc[4][4];
  #pragma unroll
  for (int m=0;m<4;m++)
    #pragma unroll
    for (int n=0;n<4;n++) acc[m][n] = (f32x4){0.f,0.f,0.f,0.f};
  const int arow = tid>>1, acb = (tid&1)*16;
  const u16* Ap = A + (size_t)(row0 + arow)*K + acb;
  const int wrow = col0 + arow;
  const bool wvalid = wrow < N;
  const size_t wro = (size_t)(wvalid ? wrow : (N-1))*K + acb;
  const u16*   Wpb = (const u16*)Wv + wro;
  const float* Wpf = (const float*)Wv + wro;

  for (int k0=0; k0<K; k0+=32){
    uint4 a0 = *(const uint4*)(Ap + k0);
    uint4 a1 = *(const uint4*)(Ap + k0 + 8);
    uint4 wp0, wp1;
    if (WBF){
      wp0 = *(const uint4*)(Wpb + k0);
      wp1 = *(const uint4*)(Wpb + k0 + 8);
    } else {
      float4 w0 = {0,0,0,0}, w1 = {0,0,0,0}, w2 = {0,0,0,0}, w3 = {0,0,0,0};
      if (wvalid){
        w0 = *(const float4*)(Wpf + k0);
        w1 = *(const float4*)(Wpf + k0 + 4);
        w2 = *(const float4*)(Wpf + k0 + 8);
        w3 = *(const float4*)(Wpf + k0 + 12);
      }
      wp0.x = pk2(w0.x,w0.y); wp0.y = pk2(w0.z,w0.w);
      wp0.z = pk2(w1.x,w1.y); wp0.w = pk2(w1.z,w1.w);
      wp1.x = pk2(w2.x,w2.y); wp1.y = pk2(w2.z,w2.w);
      wp1.z = pk2(w3.x,w3.y); wp1.w = pk2(w3.z,w3.w);
    }
    __syncthreads();
    *(uint4*)&As[arow][acb]   = a0;
    *(uint4*)&As[arow][acb+8] = a1;
    *(uint4*)&Ws[arow][acb]   = wp0;
    *(uint4*)&Ws[arow][acb+8] = wp1;
    __syncthreads();
    bf16x8 af[4], bfv[4];
    #pragma unroll
    for (int m=0;m<4;m++) af[m]  = *(const bf16x8*)&As[wr + m*16 + r16][g*8];
    #pragma unroll
    for (int n=0;n<4;n++) bfv[n] = *(const bf16x8*)&Ws[wc + n*16 + r16][g*8];
    #pragma unroll
    for (int m=0;m<4;m++)
      #pragma unroll
      for (int n=0;n<4;n++)
        acc[m][n] = __builtin_amdgcn_mfma_f32_16x16x32_bf16(af[m], bfv[n], acc[m][n], 0, 0, 0);
  }

  #pragma unroll
  for (int m=0;m<4;m++){
    #pragma unroll
    for (int n=0;n<4;n++){
      int c = col0 + wc + n*16 + r16;
      if (c < N){
        #pragma unroll
        for (int j=0;j<4;j++){
          int r = row0 + wr + m*16 + g*4 + j;
          size_t o = (size_t)r*(size_t)N + c;
          float v = acc[m][n][j];
          if (EPI == 0){
            ((float*)Cout)[o] = v;
          } else if (EPI == 1){
            ((float*)Cout)[o] += v;
          } else if (EPI == 2){
            float uu = R[o];
            float sg = v / (1.f + expf(-v));
            ((u16*)Cout)[o] = f2bf(sg * uu);
          } else {
            ((float*)Cout)[o] = 30.f * tanhf(v * (1.f/30.f));
          }
        }
      }
    }
  }
}

// ---------------- flash attention (causal), head-major bf16 in, interleaved bf16 out ----------------
__global__ __launch_bounds__(256) void k_attn(const u16* __restrict__ Qb,
    const u16* __restrict__ Kb, const u16* __restrict__ Vb, u16* __restrict__ O){
  __shared__ __align__(16) u16 Ks[32][72];
  __shared__ __align__(16) u16 Vt[64][40];
  __shared__ __align__(16) u16 Ps[4][16][40];
  const int qt = blockIdx.x, bh = blockIdx.y;
  const int b = bh >> 4, hh = bh & 15;
  const int tid = threadIdx.x, w = tid>>6, lane = tid&63, g = lane>>4, r16 = lane&15;
  const size_t base = (size_t)bh * 1024 * 64;
  const u16* Qp = Qb + base;
  const u16* Kp = Kb + base;
  const u16* Vp = Vb + base;
  const int q0 = qt*64 + w*16;
  bf16x8 qf0 = *(const bf16x8*)(Qp + (size_t)(q0 + r16)*64 + g*8);
  bf16x8 qf1 = *(const bf16x8*)(Qp + (size_t)(q0 + r16)*64 + 32 + g*8);
  f32x4 accO[4];
  #pragma unroll
  for (int n=0;n<4;n++) accO[n] = (f32x4){0.f,0.f,0.f,0.f};
  float mrow[4], lrow[4];
  #pragma unroll
  for (int j=0;j<4;j++){ mrow[j] = -1e30f; lrow[j] = 0.f; }
  const int ntiles = (qt+1)*2;
  const int srow = tid>>3, scb = (tid&7)*8;

  for (int t=0; t<ntiles; t++){
    __syncthreads();
    uint4 kv4 = *(const uint4*)(Kp + (size_t)(t*32 + srow)*64 + scb);
    *(uint4*)&Ks[srow][scb] = kv4;
    uint4 vv4 = *(const uint4*)(Vp + (size_t)(t*32 + srow)*64 + scb);
    const u16* vp = (const u16*)&vv4;
    #pragma unroll
    for (int e=0;e<8;e++) Vt[scb+e][srow] = vp[e];
    __syncthreads();

    // S = Q K^T  (two 16-col fragments)
    f32x4 s0 = (f32x4){0.f,0.f,0.f,0.f}, s1 = (f32x4){0.f,0.f,0.f,0.f};
    {
      bf16x8 k00 = *(const bf16x8*)&Ks[r16][g*8];
      bf16x8 k01 = *(const bf16x8*)&Ks[r16][32 + g*8];
      bf16x8 k10 = *(const bf16x8*)&Ks[16 + r16][g*8];
      bf16x8 k11 = *(const bf16x8*)&Ks[16 + r16][32 + g*8];
      s0 = __builtin_amdgcn_mfma_f32_16x16x32_bf16(qf0, k00, s0, 0,0,0);
      s0 = __builtin_amdgcn_mfma_f32_16x16x32_bf16(qf1, k01, s0, 0,0,0);
      s1 = __builtin_amdgcn_mfma_f32_16x16x32_bf16(qf0, k10, s1, 0,0,0);
      s1 = __builtin_amdgcn_mfma_f32_16x16x32_bf16(qf1, k11, s1, 0,0,0);
    }
    // scale + causal mask
    float sv[2][4]; float vmax[4];
    #pragma unroll
    for (int j=0;j<4;j++){
      int qg = q0 + g*4 + j;
      float a = s0[j]*0.125f; if (t*32 + r16      > qg) a = -1e30f;
      float c = s1[j]*0.125f; if (t*32 + 16 + r16 > qg) c = -1e30f;
      sv[0][j] = a; sv[1][j] = c;
      vmax[j] = fmaxf(a, c);
    }
    #pragma unroll
    for (int msk=1; msk<16; msk<<=1)
      #pragma unroll
      for (int j=0;j<4;j++) vmax[j] = fmaxf(vmax[j], __shfl_xor(vmax[j], msk, 64));
    float psum[4];
    #pragma unroll
    for (int j=0;j<4;j++){
      float mn = fmaxf(mrow[j], vmax[j]);
      float corr = expf(mrow[j] - mn);
      mrow[j] = mn;
      float p0 = expf(sv[0][j] - mn);
      float p1 = expf(sv[1][j] - mn);
      sv[0][j] = p0; sv[1][j] = p1;
      psum[j] = p0 + p1;
      lrow[j] *= corr;
      #pragma unroll
      for (int n=0;n<4;n++) accO[n][j] *= corr;
    }
    #pragma unroll
    for (int msk=1; msk<16; msk<<=1)
      #pragma unroll
      for (int j=0;j<4;j++) psum[j] += __shfl_xor(psum[j], msk, 64);
    #pragma unroll
    for (int j=0;j<4;j++) lrow[j] += psum[j];
    // P -> LDS (S-layout) then reread in A-layout
    #pragma unroll
    for (int j=0;j<4;j++){
      Ps[w][g*4+j][r16]      = f2bf(sv[0][j]);
      Ps[w][g*4+j][16 + r16] = f2bf(sv[1][j]);
    }
    __syncthreads();
    bf16x8 pf = *(const bf16x8*)&Ps[w][r16][g*8];
    #pragma unroll
    for (int n=0;n<4;n++){
      bf16x8 vf = *(const bf16x8*)&Vt[n*16 + r16][g*8];
      accO[n] = __builtin_amdgcn_mfma_f32_16x16x32_bf16(pf, vf, accO[n], 0,0,0);
    }
  }
  #pragma unroll
  for (int n=0;n<4;n++){
    #pragma unroll
    for (int j=0;j<4;j++){
      int qg = q0 + g*4 + j;
      float ov = accO[n][j] / lrow[j];
      O[((size_t)(b*1024 + qg))*1024 + hh*64 + n*16 + r16] = f2bf(ov);
    }
  }
}

// ---------------- host launch ----------------
extern "C" void kernel_launch(void* const* d_in, const int* in_sizes, int n_in,
                              void* d_out, int out_size, void* d_ws, size_t ws_size,
                              hipStream_t stream) {
  const int*   idx      = (const int*)  d_in[0];
  const float* tok_emb  = (const float*)d_in[1];
  const float* ln1_w    = (const float*)d_in[2];
  const float* qkv_w    = (const float*)d_in[3];
  const float* out_w    = (const float*)d_in[4];
  const float* ve_gate_w= (const float*)d_in[5];
  const float* ln2_w    = (const float*)d_in[6];
  const float* wg       = (const float*)d_in[7];
  const float* wu       = (const float*)d_in[8];
  const float* wd       = (const float*)d_in[9];
  const float* lnf_w    = (const float*)d_in[10];
  float* outp = (float*)d_out;

  char* wsb = (char*)d_ws;
  size_t off = 0;
  auto take = [&](size_t n){ void* p = wsb + off; off += (n + 255) & ~(size_t)255; return p; };
  float* x    = (float*)take((size_t)2048*1024*4);
  float* x0   = (float*)take((size_t)2048*1024*4);
  u16*   h    = (u16*)  take((size_t)2048*1024*2);
  float* qkv  = (float*)take((size_t)2048*3072*4);
  u16*   Qb   = (u16*)  take((size_t)2048*1024*2);
  u16*   Kb   = (u16*)  take((size_t)2048*1024*2);
  u16*   Vb   = (u16*)  take((size_t)2048*1024*2);
  u16*   Ob   = (u16*)  take((size_t)2048*1024*2);
  float* ubuf = (float*)take((size_t)2048*4096*4);
  u16*   hu   = (u16*)  take((size_t)2048*4096*2);
  float* ct   = (float*)take((size_t)1024*64*4);
  float* st   = (float*)take((size_t)1024*64*4);
  float* gate = (float*)take((size_t)2048*16*4);
  // bf16 weight mirrors (only used if ws_size is large enough)
  const size_t n_qkvw = (size_t)8*3072*1024;
  const size_t n_outw = (size_t)8*1024*1024;
  const size_t n_wg   = (size_t)8*4096*1024;
  const size_t n_wd   = (size_t)8*1024*4096;
  const size_t n_emb  = (size_t)50257*1024;
  u16* qkvwb = (u16*)take(n_qkvw*2);
  u16* outwb = (u16*)take(n_outw*2);
  u16* wgb   = (u16*)take(n_wg*2);
  u16* wub   = (u16*)take(n_wg*2);
  u16* wdb   = (u16*)take(n_wd*2);
  u16* embb  = (u16*)take(n_emb*2);
  const bool bw = (off <= ws_size);   // constant across calls -> graph-safe

  k_embed<<<2048, 256, 0, stream>>>(idx, tok_emb, x, x0);
  k_ropetab<<<256, 256, 0, stream>>>(ct, st);
  if (bw){
    k_conv<<<(int)(n_qkvw/1024), 256, 0, stream>>>(qkv_w,  qkvwb, (int)(n_qkvw/4));
    k_conv<<<(int)(n_outw/1024), 256, 0, stream>>>(out_w,  outwb, (int)(n_outw/4));
    k_conv<<<(int)(n_wg/1024),   256, 0, stream>>>(wg,     wgb,   (int)(n_wg/4));
    k_conv<<<(int)(n_wg/1024),   256, 0, stream>>>(wu,     wub,   (int)(n_wg/4));
    k_conv<<<(int)(n_wd/1024),   256, 0, stream>>>(wd,     wdb,   (int)(n_wd/4));
    k_conv<<<(int)((n_emb+1023)/1024), 256, 0, stream>>>(tok_emb, embb, (int)(n_emb/4));
  }

  for (int i=0; i<8; i++){
    k_rms<<<2048, 256, 0, stream>>>(x, ln1_w + i*1024, h);
    if (bw) k_gemm<0,1><<<dim3(16,24), 256, 0, stream>>>(h, qkvwb + (size_t)i*3072*1024, qkv, nullptr, 3072, 1024);
    else    k_gemm<0,0><<<dim3(16,24), 256, 0, stream>>>(h, qkv_w + (size_t)i*3072*1024, qkv, nullptr, 3072, 1024);
    if (i & 1)
      k_gate<<<128, 256, 0, stream>>>(h, ve_gate_w + (size_t)i*16*32, gate);
    k_ropeve<<<4096, 256, 0, stream>>>(qkv, ct, st, gate, x0, Qb, Kb, Vb, i & 1);
    k_attn<<<dim3(16,32), 256, 0, stream>>>(Qb, Kb, Vb, Ob);
    if (bw) k_gemm<1,1><<<dim3(16,8), 256, 0, stream>>>(Ob, outwb + (size_t)i*1024*1024, x, nullptr, 1024, 1024);
    else    k_gemm<1,0><<<dim3(16,8), 256, 0, stream>>>(Ob, out_w + (size_t)i*1024*1024, x, nullptr, 1024, 1024);
    k_rms<<<2048, 256, 0, stream>>>(x, ln2_w + i*1024, h);
    if (bw){
      k_gemm<0,1><<<dim3(16,32), 256, 0, stream>>>(h, wub + (size_t)i*4096*1024, ubuf, nullptr, 4096, 1024);
      k_gemm<2,1><<<dim3(16,32), 256, 0, stream>>>(h, wgb + (size_t)i*4096*1024, hu, ubuf, 4096, 1024);
      k_gemm<1,1><<<dim3(16,8), 256, 0, stream>>>(hu, wdb + (size_t)i*1024*4096, x, nullptr, 1024, 4096);
    } else {
      k_gemm<0,0><<<dim3(16,32), 256, 0, stream>>>(h, wu + (size_t)i*4096*1024, ubuf, nullptr, 4096, 1024);
      k_gemm<2,0><<<dim3(16,32), 256, 0, stream>>>(h, wg + (size_t)i*4096*1024, hu, ubuf, 4096, 1024);
      k_gemm<1,0><<<dim3(16,8), 256, 0, stream>>>(hu, wd + (size_t)i*1024*4096, x, nullptr, 1024, 4096);
    }
  }

  k_rms<<<2048, 256, 0, stream>>>(x, lnf_w, h);
  if (bw) k_gemm<3,1><<<dim3(16,393), 256, 0, stream>>>(h, embb,    outp, nullptr, 50257, 1024);
  else    k_gemm<3,0><<<dim3(16,393), 256, 0, stream>>>(h, tok_emb, outp, nullptr, 50257, 1024);
}